// Round 1
// baseline (907.176 us; speedup 1.0000x reference)
//
#include <hip/hip_runtime.h>

typedef __bf16 bf16;
typedef __bf16 bf16x8 __attribute__((ext_vector_type(8)));
typedef float f32x4 __attribute__((ext_vector_type(4)));

typedef const __attribute__((address_space(1))) void* gas1p;
typedef __attribute__((address_space(3))) void* las3p;

#define DEV static __device__ __forceinline__

DEV void gload16(const void* g, void* l) {
  __builtin_amdgcn_global_load_lds((gas1p)g, (las3p)l, 16, 0, 0);
}

DEV f32x4 mfma16(bf16x8 a, bf16x8 b, f32x4 c) {
  return __builtin_amdgcn_mfma_f32_16x16x32_bf16(a, b, c, 0, 0, 0);
}

DEV f32x4 fzero4() { f32x4 z = {0.f, 0.f, 0.f, 0.f}; return z; }
DEV bf16x8 bzero8() {
  bf16x8 v;
#pragma unroll
  for (int e = 0; e < 8; ++e) v[e] = (bf16)0.f;
  return v;
}
DEV float sigm(float x) { return 1.f / (1.f + __expf(-x)); }

// ---------------- RMSNorm: f32 in -> bf16 out --------------------------------
__global__ __launch_bounds__(256) void k_rmsnorm(const float* __restrict__ inp,
                                                 const float* __restrict__ w,
                                                 bf16* __restrict__ xb) {
  int n = blockIdx.x, tid = threadIdx.x;
  const float* row = inp + (size_t)n * 2048;
  float4 v0 = *(const float4*)(row + tid * 8);
  float4 v1 = *(const float4*)(row + tid * 8 + 4);
  float ss = v0.x * v0.x + v0.y * v0.y + v0.z * v0.z + v0.w * v0.w +
             v1.x * v1.x + v1.y * v1.y + v1.z * v1.z + v1.w * v1.w;
#pragma unroll
  for (int m = 1; m < 64; m <<= 1) ss += __shfl_xor(ss, m, 64);
  __shared__ float wsum[4];
  if ((tid & 63) == 0) wsum[tid >> 6] = ss;
  __syncthreads();
  float tot = wsum[0] + wsum[1] + wsum[2] + wsum[3];
  float scale = rsqrtf(tot * (1.0f / 2048.0f) + 1.1920928955078125e-07f);
  const float* wp = w + tid * 8;
  bf16* op = xb + (size_t)n * 2048 + tid * 8;
  float vals[8] = {v0.x, v0.y, v0.z, v0.w, v1.x, v1.y, v1.z, v1.w};
#pragma unroll
  for (int e = 0; e < 8; ++e) op[e] = (bf16)(vals[e] * scale * wp[e]);
}

// ------------- transpose+convert: f32 [R][C] -> bf16 [Cout][R] (pad 0) -------
__global__ __launch_bounds__(256) void k_transpose(const float* __restrict__ in,
                                                   bf16* __restrict__ out,
                                                   int R, int C, int Cout) {
  __shared__ float tile[32][33];
  int c0 = blockIdx.x * 32, r0 = blockIdx.y * 32;
  int tx = threadIdx.x & 31, ty = threadIdx.x >> 5;
#pragma unroll
  for (int i = 0; i < 4; ++i) {
    int r = r0 + ty + i * 8, c = c0 + tx;
    tile[ty + i * 8][tx] = (r < R && c < C) ? in[(size_t)r * C + c] : 0.0f;
  }
  __syncthreads();
#pragma unroll
  for (int i = 0; i < 4; ++i) {
    int c = c0 + ty + i * 8, r = r0 + tx;
    if (c < Cout && r < R) out[(size_t)c * R + r] = (bf16)tile[tx][ty + i * 8];
  }
}

// --- conv weights [h][o][i][t] f32 -> BcT bf16 [kv][h][o][kappa=t*64+i] ------
__global__ __launch_bounds__(256) void k_convwT(const float* __restrict__ kcw,
                                                const float* __restrict__ vcw,
                                                bf16* __restrict__ bct) {
  int slab = blockIdx.x;  // kv*2048 + h*64 + o
  const float* src = (slab < 2048 ? kcw : vcw) + (size_t)(slab & 2047) * 4096;
  bf16* dst = bct + (size_t)slab * 4096;
  __shared__ float t[64 * 65];
#pragma unroll
  for (int e = 0; e < 16; ++e) {
    int f = threadIdx.x + e * 256;  // f = i*64 + tt
    t[(f >> 6) * 65 + (f & 63)] = src[f];
  }
  __syncthreads();
#pragma unroll
  for (int e = 0; e < 16; ++e) {
    int f = threadIdx.x + e * 256;  // f = kappa = tt*64 + i
    dst[f] = (bf16)t[(f & 63) * 65 + (f >> 6)];
  }
}

// ------------- generic bf16 GEMM: C = A[M][K] @ Bt[N][K]^T -------------------
// 128x128 tile, BK=32, 4 waves (2x2 of 64x64), m97 2-barrier structure.
template <typename OutT>
__global__ __launch_bounds__(256) void k_gemm(const bf16* __restrict__ A,
                                              const bf16* __restrict__ Bt,
                                              OutT* __restrict__ C,
                                              int M, int N, int K) {
  (void)M;
  __shared__ __align__(16) bf16 aT[128 * 32];
  __shared__ __align__(16) bf16 bT[128 * 32];
  int tid = threadIdx.x, wave = tid >> 6, lane = tid & 63;
  int bm = blockIdx.y, bn = blockIdx.x;
  int wm = (wave >> 1) * 64, wn = (wave & 1) * 64;
  int la = lane & 15, lk = (lane >> 4) * 8;
  f32x4 acc[4][4];
#pragma unroll
  for (int i = 0; i < 4; ++i)
#pragma unroll
    for (int j = 0; j < 4; ++j) acc[i][j] = fzero4();
  size_t aBase = (size_t)(bm * 128) * K, bBase = (size_t)(bn * 128) * K;
  const int nk = K >> 5;
  for (int kt = 0; kt < nk; ++kt) {
    int k0 = kt * 32;
    __syncthreads();
#pragma unroll
    for (int c = 0; c < 2; ++c) {
      int chunk = c * 256 + tid;
      int row = chunk >> 2, ko = (chunk & 3) * 8;  // lds byte off == chunk*16 (lane-linear)
      gload16(A + aBase + (size_t)row * K + k0 + ko, aT + row * 32 + ko);
      gload16(Bt + bBase + (size_t)row * K + k0 + ko, bT + row * 32 + ko);
    }
    __syncthreads();
    bf16x8 af[4], bfr[4];
#pragma unroll
    for (int i = 0; i < 4; ++i) {
      af[i] = *(const bf16x8*)(aT + (wm + i * 16 + la) * 32 + lk);
      bfr[i] = *(const bf16x8*)(bT + (wn + i * 16 + la) * 32 + lk);
    }
#pragma unroll
    for (int i = 0; i < 4; ++i)
#pragma unroll
      for (int j = 0; j < 4; ++j) acc[i][j] = mfma16(af[i], bfr[j], acc[i][j]);
  }
  int rg = (lane >> 4) * 4;
#pragma unroll
  for (int i = 0; i < 4; ++i)
#pragma unroll
    for (int j = 0; j < 4; ++j)
#pragma unroll
      for (int v = 0; v < 4; ++v) {
        int r = bm * 128 + wm + i * 16 + rg + v;
        int col = bn * 128 + wn + j * 16 + la;
        C[(size_t)r * N + col] = (OutT)acc[i][j][v];
      }
}

// ------------- per-head conv GEMM: ck/cv = (k|v + pos) @ BcT^T + bias --------
// block = (kv,h). M=128(j), N=64(o), K=4096(kappa=t*64+i), A built on the fly.
__global__ __launch_bounds__(256) void k_convgemm(const bf16* __restrict__ qkv,
                                                  const float* __restrict__ kpos,
                                                  const float* __restrict__ vpos,
                                                  const float* __restrict__ kcb,
                                                  const float* __restrict__ vcb,
                                                  const bf16* __restrict__ bct,
                                                  bf16* __restrict__ ckbuf) {
  int kv = blockIdx.x >> 5, h = blockIdx.x & 31;
  const float* pos = kv ? vpos : kpos;
  const float* bias = kv ? vcb : kcb;
  int koff = 2048 + kv * 2048;
  __shared__ __align__(16) bf16 bT[64 * 32];
  int tid = threadIdx.x, wave = tid >> 6, lane = tid & 63;
  int la = lane & 15, lg = lane >> 4;
  f32x4 acc[2][4];
#pragma unroll
  for (int i = 0; i < 2; ++i)
#pragma unroll
    for (int j = 0; j < 4; ++j) acc[i][j] = fzero4();
  const bf16* bsrc = bct + (size_t)((kv * 32 + h) * 64) * 4096;
  for (int kt = 0; kt < 128; ++kt) {
    __syncthreads();
    gload16(bsrc + (size_t)(tid >> 2) * 4096 + kt * 32 + (tid & 3) * 8,
            bT + (tid >> 2) * 32 + (tid & 3) * 8);
    __syncthreads();
    int t = kt >> 1;
    int i0 = (kt & 1) * 32 + lg * 8;
    bf16x8 bf4[4];
#pragma unroll
    for (int j = 0; j < 4; ++j) bf4[j] = *(const bf16x8*)(bT + (j * 16 + la) * 32 + lg * 8);
#pragma unroll
    for (int mi = 0; mi < 2; ++mi) {
      int jrow = wave * 32 + mi * 16 + la;
      int n = jrow * 64 + t;
      bf16x8 qv = *(const bf16x8*)(qkv + (size_t)n * 6144 + koff + h * 64 + i0);
      const float* pp = pos + h * 4096 + t * 64 + i0;
      bf16x8 a;
#pragma unroll
      for (int e = 0; e < 8; ++e) a[e] = (bf16)((float)qv[e] + pp[e]);
#pragma unroll
      for (int j = 0; j < 4; ++j) acc[mi][j] = mfma16(a, bf4[j], acc[mi][j]);
    }
  }
  bf16* dst = ckbuf + (size_t)((kv * 32 + h) * 160) * 64;
#pragma unroll
  for (int mi = 0; mi < 2; ++mi)
#pragma unroll
    for (int j = 0; j < 4; ++j)
#pragma unroll
      for (int v = 0; v < 4; ++v) {
        int jr = wave * 32 + mi * 16 + lg * 4 + v;
        int o = j * 16 + la;
        dst[(size_t)(4 + jr) * 64 + o] = (bf16)(acc[mi][j][v] + bias[h * 64 + o]);
      }
}

// mem_kv rows 0..3 + zero rows 132..159 of ckbuf ------------------------------
__global__ __launch_bounds__(256) void k_fillck(const float* __restrict__ memkv,
                                                bf16* __restrict__ ckbuf) {
  int kv = blockIdx.x >> 5, h = blockIdx.x & 31;
  bf16* dst = ckbuf + (size_t)((kv * 32 + h) * 160) * 64;
  int tid = threadIdx.x;
  dst[tid] = (bf16)memkv[(size_t)(kv * 32 + h) * 256 + tid];
  for (int f = tid; f < 28 * 64; f += 256) dst[132 * 64 + f] = (bf16)0.f;
}

// ------------- local sliding-window attention --------------------------------
// block = (qb,h), 512 thr = 8 waves, each wave owns 16 query rows.
__global__ __launch_bounds__(512) void k_local(const bf16* __restrict__ qkv,
                                               bf16* __restrict__ lout) {
  int qb = blockIdx.x, h = blockIdx.y;
  __shared__ __align__(16) bf16 kl[256 * 72];
  __shared__ __align__(16) bf16 vT[64 * 264];
  __shared__ __align__(16) bf16 pl[128 * 264];
  int tid = threadIdx.x, wave = tid >> 6, lane = tid & 63;
  int la = lane & 15, lg = lane >> 4;
#pragma unroll
  for (int it = 0; it < 4; ++it) {
    int c = it * 512 + tid;
    int row = c >> 3, off = (c & 7) * 8;
    int n = qb * 128 - 128 + row;
    bf16x8 kvr = bzero8(), vvr = bzero8();
    if (n >= 0) {
      kvr = *(const bf16x8*)(qkv + (size_t)n * 6144 + 2048 + h * 64 + off);
      vvr = *(const bf16x8*)(qkv + (size_t)n * 6144 + 4096 + h * 64 + off);
    }
    *(bf16x8*)(kl + row * 72 + off) = kvr;
#pragma unroll
    for (int e = 0; e < 8; ++e) vT[(off + e) * 264 + row] = vvr[e];
  }
  int nq = qb * 128 + wave * 16 + la;
  bf16x8 aq0 = *(const bf16x8*)(qkv + (size_t)nq * 6144 + h * 64 + lg * 8);
  bf16x8 aq1 = *(const bf16x8*)(qkv + (size_t)nq * 6144 + h * 64 + 32 + lg * 8);
  __syncthreads();
  f32x4 s[16];
#pragma unroll
  for (int nf = 0; nf < 16; ++nf) {
    bf16x8 b0 = *(const bf16x8*)(kl + (nf * 16 + la) * 72 + lg * 8);
    bf16x8 b1 = *(const bf16x8*)(kl + (nf * 16 + la) * 72 + 32 + lg * 8);
    f32x4 t = fzero4();
    t = mfma16(aq0, b0, t);
    t = mfma16(aq1, b1, t);
    s[nf] = t;
  }
  float mx[4] = {-1e30f, -1e30f, -1e30f, -1e30f};
#pragma unroll
  for (int nf = 0; nf < 16; ++nf)
#pragma unroll
    for (int v = 0; v < 4; ++v) {
      int iq = wave * 16 + lg * 4 + v;
      int jj = nf * 16 + la;
      bool ok = (jj >= iq) && (jj <= iq + 128) && (qb > 0 || jj >= 128);
      float sv = ok ? s[nf][v] * 0.125f : -1e30f;
      s[nf][v] = sv;
      mx[v] = fmaxf(mx[v], sv);
    }
#pragma unroll
  for (int v = 0; v < 4; ++v)
#pragma unroll
    for (int m = 1; m < 16; m <<= 1) mx[v] = fmaxf(mx[v], __shfl_xor(mx[v], m, 64));
  float den[4] = {0.f, 0.f, 0.f, 0.f};
#pragma unroll
  for (int nf = 0; nf < 16; ++nf)
#pragma unroll
    for (int v = 0; v < 4; ++v) {
      float p = __expf(s[nf][v] - mx[v]);
      s[nf][v] = p;
      den[v] += p;
    }
#pragma unroll
  for (int v = 0; v < 4; ++v)
#pragma unroll
    for (int m = 1; m < 16; m <<= 1) den[v] += __shfl_xor(den[v], m, 64);
#pragma unroll
  for (int nf = 0; nf < 16; ++nf)
#pragma unroll
    for (int v = 0; v < 4; ++v)
      pl[(wave * 16 + lg * 4 + v) * 264 + nf * 16 + la] = (bf16)s[nf][v];
  __syncthreads();
  bf16x8 ap[8];
#pragma unroll
  for (int kk = 0; kk < 8; ++kk)
    ap[kk] = *(const bf16x8*)(pl + (wave * 16 + la) * 264 + kk * 32 + lg * 8);
  f32x4 o[4];
#pragma unroll
  for (int j = 0; j < 4; ++j) o[j] = fzero4();
#pragma unroll
  for (int j = 0; j < 4; ++j)
#pragma unroll
    for (int kk = 0; kk < 8; ++kk) {
      bf16x8 b = *(const bf16x8*)(vT + (j * 16 + la) * 264 + kk * 32 + lg * 8);
      o[j] = mfma16(ap[kk], b, o[j]);
    }
#pragma unroll
  for (int j = 0; j < 4; ++j)
#pragma unroll
    for (int v = 0; v < 4; ++v) {
      int n = qb * 128 + wave * 16 + lg * 4 + v;
      int d = j * 16 + la;
      lout[(size_t)n * 2048 + h * 64 + d] = (bf16)(o[j][v] / den[v]);
    }
}

// ------------- compressed attention (132 keys, padded to 160) ----------------
__global__ __launch_bounds__(512) void k_comp(const bf16* __restrict__ qkv,
                                              const bf16* __restrict__ ckbuf,
                                              bf16* __restrict__ cout) {
  int qb = blockIdx.x, h = blockIdx.y;
  __shared__ __align__(16) bf16 ckl[160 * 72];
  __shared__ __align__(16) bf16 cvT[64 * 168];
  __shared__ __align__(16) bf16 pl[128 * 168];
  int tid = threadIdx.x, wave = tid >> 6, lane = tid & 63;
  int la = lane & 15, lg = lane >> 4;
  const bf16* cks = ckbuf + (size_t)(h * 160) * 64;
  const bf16* cvs = ckbuf + (size_t)((32 + h) * 160) * 64;
  for (int c = tid; c < 1280; c += 512) {
    int row = c >> 3, off = (c & 7) * 8;
    *(bf16x8*)(ckl + row * 72 + off) = *(const bf16x8*)(cks + row * 64 + off);
    bf16x8 vv = *(const bf16x8*)(cvs + row * 64 + off);
#pragma unroll
    for (int e = 0; e < 8; ++e) cvT[(off + e) * 168 + row] = vv[e];
  }
  int nq = qb * 128 + wave * 16 + la;
  bf16x8 aq0 = *(const bf16x8*)(qkv + (size_t)nq * 6144 + h * 64 + lg * 8);
  bf16x8 aq1 = *(const bf16x8*)(qkv + (size_t)nq * 6144 + h * 64 + 32 + lg * 8);
  __syncthreads();
  f32x4 s[10];
#pragma unroll
  for (int nf = 0; nf < 10; ++nf) {
    bf16x8 b0 = *(const bf16x8*)(ckl + (nf * 16 + la) * 72 + lg * 8);
    bf16x8 b1 = *(const bf16x8*)(ckl + (nf * 16 + la) * 72 + 32 + lg * 8);
    f32x4 t = fzero4();
    t = mfma16(aq0, b0, t);
    t = mfma16(aq1, b1, t);
    s[nf] = t;
  }
  int bi = qb * 2 + (wave >> 2);  // query block index i>>6, uniform per wave
  float mx[4] = {-1e30f, -1e30f, -1e30f, -1e30f};
#pragma unroll
  for (int nf = 0; nf < 10; ++nf)
#pragma unroll
    for (int v = 0; v < 4; ++v) {
      int jj = nf * 16 + la;
      bool ok = (jj >= 4 + bi) && (jj < 132);
      float sv = ok ? s[nf][v] * 0.125f : -1e30f;
      s[nf][v] = sv;
      mx[v] = fmaxf(mx[v], sv);
    }
#pragma unroll
  for (int v = 0; v < 4; ++v)
#pragma unroll
    for (int m = 1; m < 16; m <<= 1) mx[v] = fmaxf(mx[v], __shfl_xor(mx[v], m, 64));
  float den[4] = {0.f, 0.f, 0.f, 0.f};
#pragma unroll
  for (int nf = 0; nf < 10; ++nf)
#pragma unroll
    for (int v = 0; v < 4; ++v) {
      float p = __expf(s[nf][v] - mx[v]);
      s[nf][v] = p;
      den[v] += p;
    }
#pragma unroll
  for (int v = 0; v < 4; ++v)
#pragma unroll
    for (int m = 1; m < 16; m <<= 1) den[v] += __shfl_xor(den[v], m, 64);
#pragma unroll
  for (int nf = 0; nf < 10; ++nf)
#pragma unroll
    for (int v = 0; v < 4; ++v)
      pl[(wave * 16 + lg * 4 + v) * 168 + nf * 16 + la] = (bf16)s[nf][v];
  __syncthreads();
  bf16x8 ap[5];
#pragma unroll
  for (int kk = 0; kk < 5; ++kk)
    ap[kk] = *(const bf16x8*)(pl + (wave * 16 + la) * 168 + kk * 32 + lg * 8);
  f32x4 o[4];
#pragma unroll
  for (int j = 0; j < 4; ++j) o[j] = fzero4();
#pragma unroll
  for (int j = 0; j < 4; ++j)
#pragma unroll
    for (int kk = 0; kk < 5; ++kk) {
      bf16x8 b = *(const bf16x8*)(cvT + (j * 16 + la) * 168 + kk * 32 + lg * 8);
      o[j] = mfma16(ap[kk], b, o[j]);
    }
#pragma unroll
  for (int j = 0; j < 4; ++j)
#pragma unroll
    for (int v = 0; v < 4; ++v) {
      int n = qb * 128 + wave * 16 + lg * 4 + v;
      int d = j * 16 + la;
      cout[(size_t)n * 2048 + h * 64 + d] = (bf16)(o[j][v] / den[v]);
    }
}

// ------------- combine: att = (s0+s1)*local + s2*comp ------------------------
__global__ __launch_bounds__(256) void k_combine(const bf16* __restrict__ lo,
                                                 const bf16* __restrict__ co,
                                                 const float* __restrict__ comb,
                                                 const float* __restrict__ bcomb,
                                                 bf16* __restrict__ att) {
  size_t idx = (size_t)blockIdx.x * 256 + threadIdx.x;
  size_t base = idx * 8;
  int n = (int)(base >> 11);
  int hd = (int)(base & 2047);
  int h = hd >> 6;
  const float* cb = comb + (size_t)n * 128 + h * 3;
  float s0 = sigm(cb[0] + bcomb[h * 3 + 0]);
  float s1 = sigm(cb[1] + bcomb[h * 3 + 1]);
  float s2 = sigm(cb[2] + bcomb[h * 3 + 2]);
  float wl = s0 + s1;
  bf16x8 l = *(const bf16x8*)(lo + base);
  bf16x8 c = *(const bf16x8*)(co + base);
  bf16x8 r;
#pragma unroll
  for (int e = 0; e < 8; ++e) r[e] = (bf16)(wl * (float)l[e] + s2 * (float)c[e]);
  *(bf16x8*)(att + base) = r;
}

// ============================================================================
extern "C" void kernel_launch(void* const* d_in, const int* in_sizes, int n_in,
                              void* d_out, int out_size, void* d_ws, size_t ws_size,
                              hipStream_t stream) {
  const float* inp = (const float*)d_in[0];
  const float* rmsw = (const float*)d_in[1];
  const float* wqkv = (const float*)d_in[2];
  const float* kpos = (const float*)d_in[3];
  const float* vpos = (const float*)d_in[4];
  const float* kcw = (const float*)d_in[5];
  const float* kcb = (const float*)d_in[6];
  const float* vcw = (const float*)d_in[7];
  const float* vcb = (const float*)d_in[8];
  const float* memkv = (const float*)d_in[9];
  const float* wcomb = (const float*)d_in[10];
  const float* bcomb = (const float*)d_in[11];
  const float* wout = (const float*)d_in[12];
  float* out = (float*)d_out;

  char* ws = (char*)d_ws;
  size_t off = 0;
  auto alloc = [&](size_t bytes) {
    void* p = ws + off;
    off += (bytes + 255) & ~(size_t)255;
    return p;
  };
  bf16* qkv = (bf16*)alloc(100663296);    // [8192][6144]
  bf16* regX = (bf16*)alloc(33554432);    // x_bf16, later att
  bf16* regT1 = (bf16*)alloc(33554432);   // w_qkvT, later comp_out
  bf16* regT2 = (bf16*)alloc(33554432);   // BcT, later local_out
  bf16* woutT = (bf16*)alloc(8388608);    // [2048][2048]
  bf16* wcombT = (bf16*)alloc(524288);    // [128][2048] (zero-padded 96->128)
  bf16* ckbuf = (bf16*)alloc(1310720);    // [2][32][160][64]
  float* combb = (float*)alloc(4194304);  // [8192][128]

  bf16* xb = regX;
  bf16* wqkvT = regT1;
  bf16* bct = regT2;

  // 1. RMSNorm -> x bf16
  k_rmsnorm<<<8192, 256, 0, stream>>>(inp, rmsw, xb);
  // 2. weight transposes/converts
  k_transpose<<<dim3(192, 64), 256, 0, stream>>>(wqkv, wqkvT, 2048, 6144, 6144);
  k_transpose<<<dim3(64, 64), 256, 0, stream>>>(wout, woutT, 2048, 2048, 2048);
  k_transpose<<<dim3(4, 64), 256, 0, stream>>>(wcomb, wcombT, 2048, 96, 128);
  k_convwT<<<4096, 256, 0, stream>>>(kcw, vcw, bct);
  // 3. QKV projection (dominant GEMM)
  k_gemm<bf16><<<dim3(48, 64), 256, 0, stream>>>(xb, wqkvT, qkv, 8192, 6144, 2048);
  // 4. combine-gate projection (pre-sigmoid)
  k_gemm<float><<<dim3(1, 64), 256, 0, stream>>>(xb, wcombT, combb, 8192, 128, 2048);
  // 5. compressed K/V: mem rows + zero pad, then per-head conv GEMM
  k_fillck<<<64, 256, 0, stream>>>(memkv, ckbuf);
  k_convgemm<<<64, 256, 0, stream>>>(qkv, kpos, vpos, kcb, vcb, bct, ckbuf);
  // 6. local sliding-window attention (overwrites BcT region)
  bf16* lout = regT2;
  k_local<<<dim3(64, 32), 512, 0, stream>>>(qkv, lout);
  // 7. compressed attention (overwrites w_qkvT region)
  bf16* cout = regT1;
  k_comp<<<dim3(64, 32), 512, 0, stream>>>(qkv, ckbuf, cout);
  // 8. sigmoid combine (overwrites x region)
  bf16* att = regX;
  k_combine<<<8192, 256, 0, stream>>>(lout, cout, combb, bcomb, att);
  // 9. output projection
  k_gemm<float><<<dim3(16, 64), 256, 0, stream>>>(att, woutT, out, 8192, 2048, 2048);
  (void)in_sizes; (void)n_in; (void)out_size; (void)ws_size;
}

// Round 2
// 812.262 us; speedup vs baseline: 1.1169x; 1.1169x over previous
//
#include <hip/hip_runtime.h>

typedef __bf16 bf16;
typedef __bf16 bf16x8 __attribute__((ext_vector_type(8)));
typedef float f32x4 __attribute__((ext_vector_type(4)));

typedef const __attribute__((address_space(1))) void* gas1p;
typedef __attribute__((address_space(3))) void* las3p;

#define DEV static __device__ __forceinline__

DEV void gload16(const void* g, void* l) {
  __builtin_amdgcn_global_load_lds((gas1p)g, (las3p)l, 16, 0, 0);
}

DEV f32x4 mfma16(bf16x8 a, bf16x8 b, f32x4 c) {
  return __builtin_amdgcn_mfma_f32_16x16x32_bf16(a, b, c, 0, 0, 0);
}

DEV f32x4 fzero4() { f32x4 z = {0.f, 0.f, 0.f, 0.f}; return z; }
DEV bf16x8 bzero8() {
  bf16x8 v;
#pragma unroll
  for (int e = 0; e < 8; ++e) v[e] = (bf16)0.f;
  return v;
}
DEV float sigm(float x) { return 1.f / (1.f + __expf(-x)); }

// ---------------- RMSNorm: f32 in -> bf16 out --------------------------------
__global__ __launch_bounds__(256) void k_rmsnorm(const float* __restrict__ inp,
                                                 const float* __restrict__ w,
                                                 bf16* __restrict__ xb) {
  int n = blockIdx.x, tid = threadIdx.x;
  const float* row = inp + (size_t)n * 2048;
  float4 v0 = *(const float4*)(row + tid * 8);
  float4 v1 = *(const float4*)(row + tid * 8 + 4);
  float ss = v0.x * v0.x + v0.y * v0.y + v0.z * v0.z + v0.w * v0.w +
             v1.x * v1.x + v1.y * v1.y + v1.z * v1.z + v1.w * v1.w;
#pragma unroll
  for (int m = 1; m < 64; m <<= 1) ss += __shfl_xor(ss, m, 64);
  __shared__ float wsum[4];
  if ((tid & 63) == 0) wsum[tid >> 6] = ss;
  __syncthreads();
  float tot = wsum[0] + wsum[1] + wsum[2] + wsum[3];
  float scale = rsqrtf(tot * (1.0f / 2048.0f) + 1.1920928955078125e-07f);
  const float* wp = w + tid * 8;
  bf16* op = xb + (size_t)n * 2048 + tid * 8;
  float vals[8] = {v0.x, v0.y, v0.z, v0.w, v1.x, v1.y, v1.z, v1.w};
#pragma unroll
  for (int e = 0; e < 8; ++e) op[e] = (bf16)(vals[e] * scale * wp[e]);
}

// ------------- transpose+convert: f32 [R][C] -> bf16 [Cout][R] (pad 0) -------
__global__ __launch_bounds__(256) void k_transpose(const float* __restrict__ in,
                                                   bf16* __restrict__ out,
                                                   int R, int C, int Cout) {
  __shared__ float tile[32][33];
  int c0 = blockIdx.x * 32, r0 = blockIdx.y * 32;
  int tx = threadIdx.x & 31, ty = threadIdx.x >> 5;
#pragma unroll
  for (int i = 0; i < 4; ++i) {
    int r = r0 + ty + i * 8, c = c0 + tx;
    tile[ty + i * 8][tx] = (r < R && c < C) ? in[(size_t)r * C + c] : 0.0f;
  }
  __syncthreads();
#pragma unroll
  for (int i = 0; i < 4; ++i) {
    int c = c0 + ty + i * 8, r = r0 + tx;
    if (c < Cout && r < R) out[(size_t)c * R + r] = (bf16)tile[tx][ty + i * 8];
  }
}

// --- conv weights [h][o][i][t] f32 -> BcT bf16 [kv][h][o][kappa=t*64+i] ------
__global__ __launch_bounds__(256) void k_convwT(const float* __restrict__ kcw,
                                                const float* __restrict__ vcw,
                                                bf16* __restrict__ bct) {
  int slab = blockIdx.x;  // kv*2048 + h*64 + o
  const float* src = (slab < 2048 ? kcw : vcw) + (size_t)(slab & 2047) * 4096;
  bf16* dst = bct + (size_t)slab * 4096;
  __shared__ float t[64 * 65];
#pragma unroll
  for (int e = 0; e < 16; ++e) {
    int f = threadIdx.x + e * 256;  // f = i*64 + tt
    t[(f >> 6) * 65 + (f & 63)] = src[f];
  }
  __syncthreads();
#pragma unroll
  for (int e = 0; e < 16; ++e) {
    int f = threadIdx.x + e * 256;  // f = kappa = tt*64 + i
    dst[f] = (bf16)t[(f & 63) * 65 + (f >> 6)];
  }
}

// ------------- generic bf16 GEMM (128x128, m97 structure) --------------------
// kept for the small combine-gate GEMM (N=128)
template <typename OutT>
__global__ __launch_bounds__(256) void k_gemm(const bf16* __restrict__ A,
                                              const bf16* __restrict__ Bt,
                                              OutT* __restrict__ C,
                                              int M, int N, int K) {
  (void)M;
  __shared__ __align__(16) bf16 aT[128 * 32];
  __shared__ __align__(16) bf16 bT[128 * 32];
  int tid = threadIdx.x, wave = tid >> 6, lane = tid & 63;
  int bm = blockIdx.y, bn = blockIdx.x;
  int wm = (wave >> 1) * 64, wn = (wave & 1) * 64;
  int la = lane & 15, lk = (lane >> 4) * 8;
  f32x4 acc[4][4];
#pragma unroll
  for (int i = 0; i < 4; ++i)
#pragma unroll
    for (int j = 0; j < 4; ++j) acc[i][j] = fzero4();
  size_t aBase = (size_t)(bm * 128) * K, bBase = (size_t)(bn * 128) * K;
  const int nk = K >> 5;
  for (int kt = 0; kt < nk; ++kt) {
    int k0 = kt * 32;
    __syncthreads();
#pragma unroll
    for (int c = 0; c < 2; ++c) {
      int chunk = c * 256 + tid;
      int row = chunk >> 2, ko = (chunk & 3) * 8;
      gload16(A + aBase + (size_t)row * K + k0 + ko, aT + row * 32 + ko);
      gload16(Bt + bBase + (size_t)row * K + k0 + ko, bT + row * 32 + ko);
    }
    __syncthreads();
    bf16x8 af[4], bfr[4];
#pragma unroll
    for (int i = 0; i < 4; ++i) {
      af[i] = *(const bf16x8*)(aT + (wm + i * 16 + la) * 32 + lk);
      bfr[i] = *(const bf16x8*)(bT + (wn + i * 16 + la) * 32 + lk);
    }
#pragma unroll
    for (int i = 0; i < 4; ++i)
#pragma unroll
      for (int j = 0; j < 4; ++j) acc[i][j] = mfma16(af[i], bfr[j], acc[i][j]);
  }
  int rg = (lane >> 4) * 4;
#pragma unroll
  for (int i = 0; i < 4; ++i)
#pragma unroll
    for (int j = 0; j < 4; ++j)
#pragma unroll
      for (int v = 0; v < 4; ++v) {
        int r = bm * 128 + wm + i * 16 + rg + v;
        int col = bn * 128 + wn + j * 16 + la;
        C[(size_t)r * N + col] = (OutT)acc[i][j][v];
      }
}

// ============ 256x256 8-phase GEMM (T1+T2+T3+T4+T5) ==========================
// A[M][K] bf16, Bt[N][K] bf16, C[M][N]. BK=64, 8 waves (2Mx4N of 64x32 per
// quadrant-phase). 4 half-slots per operand (16 KiB each). Swizzled LDS via
// pre-swizzled global source (linear gload_lds dest) + XOR on ds_read.
DEV bf16x8 ldsfrag(const char* slot, int row, int ks, int lg) {
  int off = (row << 7) + ((((ks << 6) | (lg << 4))) ^ ((row & 7) << 4));
  return *(const bf16x8*)(slot + off);
}

#define READ_A(SLOT)                                                      \
  _Pragma("unroll") for (int m_ = 0; m_ < 4; ++m_)                        \
      _Pragma("unroll") for (int ks_ = 0; ks_ < 2; ++ks_)                 \
          afr[m_][ks_] = ldsfrag(SLOT, wr64 + m_ * 16 + la, ks_, lg);

#define READ_B(SLOT)                                                      \
  _Pragma("unroll") for (int n_ = 0; n_ < 2; ++n_)                        \
      _Pragma("unroll") for (int ks_ = 0; ks_ < 2; ++ks_)                 \
          bfr[n_][ks_] = ldsfrag(SLOT, wc32 + n_ * 16 + la, ks_, lg);

#define MFMA_PHASE(MQ, NQ)                                                \
  __builtin_amdgcn_s_setprio(1);                                          \
  _Pragma("unroll") for (int m_ = 0; m_ < 4; ++m_)                        \
      _Pragma("unroll") for (int n_ = 0; n_ < 2; ++n_)                    \
          _Pragma("unroll") for (int ks_ = 0; ks_ < 2; ++ks_) acc[MQ][NQ] \
              [m_][n_] = mfma16(afr[m_][ks_], bfr[n_][ks_],               \
                                acc[MQ][NQ][m_][n_]);                     \
  __builtin_amdgcn_s_setprio(0);

#define BAR() __builtin_amdgcn_s_barrier()

template <typename OutT>
__global__ __launch_bounds__(512, 2) void k_gemm256(const bf16* __restrict__ A,
                                                    const bf16* __restrict__ Bt,
                                                    OutT* __restrict__ C,
                                                    int M, int N, int K) {
  (void)M;
  __shared__ __align__(16) char LB[131072];  // A: [0,64K) 4 slots; B: [64K,128K)
  const int tid = threadIdx.x;
  const int lane = tid & 63, wave = tid >> 6;
  const int la = lane & 15, lg = lane >> 4;
  const int wr64 = (wave >> 2) * 64, wc32 = (wave & 3) * 32;
  const int nbn = N >> 8;
  const int nwg = gridDim.x, wg = blockIdx.x;
  const int swz = (wg & 7) * (nwg >> 3) + (wg >> 3);  // XCD swizzle (nwg%8==0)
  const int bm = swz / nbn, bn = swz % nbn;
  const int NK = K >> 6;

  const bf16* aT0 = A + (size_t)(bm * 256) * K;
  const bf16* aT1 = A + (size_t)(bm * 256 + 128) * K;
  const bf16* bT0 = Bt + (size_t)(bn * 256) * K;
  const bf16* bT1 = Bt + (size_t)(bn * 256 + 128) * K;
  // per-thread staging offsets: granule g -> row r=g>>3, col k0=((g&7)^(r&7))*8
  const int g1 = tid + 512;
  const size_t sOff0 = (size_t)(tid >> 3) * K + (((tid & 7) ^ ((tid >> 3) & 7)) << 3);
  const size_t sOff1 = (size_t)(g1 >> 3) * K + (((g1 & 7) ^ ((g1 >> 3) & 7)) << 3);
  const int dOff0 = tid * 16, dOff1 = g1 * 16;
  char* AS = LB;
  char* BS = LB + 65536;

  auto stage = [&](const bf16* base, int kt, char* slot) {
    gload16(base + sOff0 + kt * 64, slot + dOff0);
    gload16(base + sOff1 + kt * 64, slot + dOff1);
  };

  f32x4 acc[2][2][4][2];
#pragma unroll
  for (int a = 0; a < 2; ++a)
#pragma unroll
    for (int b = 0; b < 2; ++b)
#pragma unroll
      for (int m = 0; m < 4; ++m)
#pragma unroll
        for (int n = 0; n < 2; ++n) acc[a][b][m][n] = fzero4();

  // prologue: tile0 (4 halves) + tile1 h0 of A,B -> wait 4 oldest half-tiles
  stage(aT0, 0, AS + 0 * 16384);
  stage(aT1, 0, AS + 1 * 16384);
  stage(bT0, 0, BS + 0 * 16384);
  stage(bT1, 0, BS + 1 * 16384);
  stage(aT0, 1, AS + 2 * 16384);
  stage(bT0, 1, BS + 2 * 16384);
  asm volatile("s_waitcnt vmcnt(4)" ::: "memory");
  BAR();

  bf16x8 afr[4][2], bfr[2][2];
  for (int kt = 0; kt < NK; ++kt) {
    const int par = kt & 1;
    char* aCur0 = AS + (par * 2 + 0) * 16384;
    char* aCur1 = AS + (par * 2 + 1) * 16384;
    char* bCur0 = BS + (par * 2 + 0) * 16384;
    char* bCur1 = BS + (par * 2 + 1) * 16384;
    char* aNxt1 = AS + ((par ^ 1) * 2 + 1) * 16384;
    char* bNxt1 = BS + ((par ^ 1) * 2 + 1) * 16384;
    // P1 (mq0,nq0): stage A(kt+1)h1
    READ_A(aCur0);
    READ_B(bCur0);
    if (kt + 1 < NK) stage(aT1, kt + 1, aNxt1);
    BAR();
    MFMA_PHASE(0, 0);
    BAR();
    // P2 (0,1): A reused; stage B(kt+1)h1
    READ_B(bCur1);
    if (kt + 1 < NK) stage(bT1, kt + 1, bNxt1);
    BAR();
    MFMA_PHASE(0, 1);
    BAR();
    // P3 (1,0): stage A(kt+2)h0 into aCur0 (last read at P1)
    READ_A(aCur1);
    READ_B(bCur0);
    if (kt + 2 < NK) stage(aT0, kt + 2, aCur0);
    BAR();
    MFMA_PHASE(1, 0);
    BAR();
    // P4 (1,1): stage B(kt+2)h0 into bCur0 (last read at P3); counted vmcnt
    READ_B(bCur1);
    if (kt + 2 < NK) stage(bT0, kt + 2, bCur0);
    BAR();
    MFMA_PHASE(1, 1);
    if (kt < NK - 2) {
      asm volatile("s_waitcnt vmcnt(4)" ::: "memory");
    } else {
      asm volatile("s_waitcnt vmcnt(0)" ::: "memory");
    }
    BAR();
  }

#pragma unroll
  for (int mq = 0; mq < 2; ++mq)
#pragma unroll
    for (int nq = 0; nq < 2; ++nq)
#pragma unroll
      for (int m = 0; m < 4; ++m)
#pragma unroll
        for (int n = 0; n < 2; ++n)
#pragma unroll
          for (int v = 0; v < 4; ++v) {
            int row = bm * 256 + mq * 128 + wr64 + m * 16 + lg * 4 + v;
            int col = bn * 256 + nq * 128 + wc32 + n * 16 + la;
            C[(size_t)row * N + col] = (OutT)acc[mq][nq][m][n][v];
          }
}

// ------------- per-head conv GEMM: ck/cv = (k|v + pos) @ BcT^T + bias --------
__global__ __launch_bounds__(256) void k_convgemm(const bf16* __restrict__ qkv,
                                                  const float* __restrict__ kpos,
                                                  const float* __restrict__ vpos,
                                                  const float* __restrict__ kcb,
                                                  const float* __restrict__ vcb,
                                                  const bf16* __restrict__ bct,
                                                  bf16* __restrict__ ckbuf) {
  int kv = blockIdx.x >> 5, h = blockIdx.x & 31;
  const float* pos = kv ? vpos : kpos;
  const float* bias = kv ? vcb : kcb;
  int koff = 2048 + kv * 2048;
  __shared__ __align__(16) bf16 bT[64 * 32];
  int tid = threadIdx.x, wave = tid >> 6, lane = tid & 63;
  int la = lane & 15, lg = lane >> 4;
  f32x4 acc[2][4];
#pragma unroll
  for (int i = 0; i < 2; ++i)
#pragma unroll
    for (int j = 0; j < 4; ++j) acc[i][j] = fzero4();
  const bf16* bsrc = bct + (size_t)((kv * 32 + h) * 64) * 4096;
  for (int kt = 0; kt < 128; ++kt) {
    __syncthreads();
    gload16(bsrc + (size_t)(tid >> 2) * 4096 + kt * 32 + (tid & 3) * 8,
            bT + (tid >> 2) * 32 + (tid & 3) * 8);
    __syncthreads();
    int t = kt >> 1;
    int i0 = (kt & 1) * 32 + lg * 8;
    bf16x8 bf4[4];
#pragma unroll
    for (int j = 0; j < 4; ++j) bf4[j] = *(const bf16x8*)(bT + (j * 16 + la) * 32 + lg * 8);
#pragma unroll
    for (int mi = 0; mi < 2; ++mi) {
      int jrow = wave * 32 + mi * 16 + la;
      int n = jrow * 64 + t;
      bf16x8 qv = *(const bf16x8*)(qkv + (size_t)n * 6144 + koff + h * 64 + i0);
      const float* pp = pos + h * 4096 + t * 64 + i0;
      bf16x8 a;
#pragma unroll
      for (int e = 0; e < 8; ++e) a[e] = (bf16)((float)qv[e] + pp[e]);
#pragma unroll
      for (int j = 0; j < 4; ++j) acc[mi][j] = mfma16(a, bf4[j], acc[mi][j]);
    }
  }
  bf16* dst = ckbuf + (size_t)((kv * 32 + h) * 160) * 64;
#pragma unroll
  for (int mi = 0; mi < 2; ++mi)
#pragma unroll
    for (int j = 0; j < 4; ++j)
#pragma unroll
      for (int v = 0; v < 4; ++v) {
        int jr = wave * 32 + mi * 16 + lg * 4 + v;
        int o = j * 16 + la;
        dst[(size_t)(4 + jr) * 64 + o] = (bf16)(acc[mi][j][v] + bias[h * 64 + o]);
      }
}

// mem_kv rows 0..3 + zero rows 132..159 of ckbuf ------------------------------
__global__ __launch_bounds__(256) void k_fillck(const float* __restrict__ memkv,
                                                bf16* __restrict__ ckbuf) {
  int kv = blockIdx.x >> 5, h = blockIdx.x & 31;
  bf16* dst = ckbuf + (size_t)((kv * 32 + h) * 160) * 64;
  int tid = threadIdx.x;
  dst[tid] = (bf16)memkv[(size_t)(kv * 32 + h) * 256 + tid];
  for (int f = tid; f < 28 * 64; f += 256) dst[132 * 64 + f] = (bf16)0.f;
}

// ------------- local sliding-window attention --------------------------------
__global__ __launch_bounds__(512) void k_local(const bf16* __restrict__ qkv,
                                               bf16* __restrict__ lout) {
  int qb = blockIdx.x, h = blockIdx.y;
  __shared__ __align__(16) bf16 kl[256 * 72];
  __shared__ __align__(16) bf16 vT[64 * 264];
  __shared__ __align__(16) bf16 pl[128 * 264];
  int tid = threadIdx.x, wave = tid >> 6, lane = tid & 63;
  int la = lane & 15, lg = lane >> 4;
#pragma unroll
  for (int it = 0; it < 4; ++it) {
    int c = it * 512 + tid;
    int row = c >> 3, off = (c & 7) * 8;
    int n = qb * 128 - 128 + row;
    bf16x8 kvr = bzero8(), vvr = bzero8();
    if (n >= 0) {
      kvr = *(const bf16x8*)(qkv + (size_t)n * 6144 + 2048 + h * 64 + off);
      vvr = *(const bf16x8*)(qkv + (size_t)n * 6144 + 4096 + h * 64 + off);
    }
    *(bf16x8*)(kl + row * 72 + off) = kvr;
#pragma unroll
    for (int e = 0; e < 8; ++e) vT[(off + e) * 264 + row] = vvr[e];
  }
  int nq = qb * 128 + wave * 16 + la;
  bf16x8 aq0 = *(const bf16x8*)(qkv + (size_t)nq * 6144 + h * 64 + lg * 8);
  bf16x8 aq1 = *(const bf16x8*)(qkv + (size_t)nq * 6144 + h * 64 + 32 + lg * 8);
  __syncthreads();
  f32x4 s[16];
#pragma unroll
  for (int nf = 0; nf < 16; ++nf) {
    bf16x8 b0 = *(const bf16x8*)(kl + (nf * 16 + la) * 72 + lg * 8);
    bf16x8 b1 = *(const bf16x8*)(kl + (nf * 16 + la) * 72 + 32 + lg * 8);
    f32x4 t = fzero4();
    t = mfma16(aq0, b0, t);
    t = mfma16(aq1, b1, t);
    s[nf] = t;
  }
  float mx[4] = {-1e30f, -1e30f, -1e30f, -1e30f};
#pragma unroll
  for (int nf = 0; nf < 16; ++nf)
#pragma unroll
    for (int v = 0; v < 4; ++v) {
      int iq = wave * 16 + lg * 4 + v;
      int jj = nf * 16 + la;
      bool ok = (jj >= iq) && (jj <= iq + 128) && (qb > 0 || jj >= 128);
      float sv = ok ? s[nf][v] * 0.125f : -1e30f;
      s[nf][v] = sv;
      mx[v] = fmaxf(mx[v], sv);
    }
#pragma unroll
  for (int v = 0; v < 4; ++v)
#pragma unroll
    for (int m = 1; m < 16; m <<= 1) mx[v] = fmaxf(mx[v], __shfl_xor(mx[v], m, 64));
  float den[4] = {0.f, 0.f, 0.f, 0.f};
#pragma unroll
  for (int nf = 0; nf < 16; ++nf)
#pragma unroll
    for (int v = 0; v < 4; ++v) {
      float p = __expf(s[nf][v] - mx[v]);
      s[nf][v] = p;
      den[v] += p;
    }
#pragma unroll
  for (int v = 0; v < 4; ++v)
#pragma unroll
    for (int m = 1; m < 16; m <<= 1) den[v] += __shfl_xor(den[v], m, 64);
#pragma unroll
  for (int nf = 0; nf < 16; ++nf)
#pragma unroll
    for (int v = 0; v < 4; ++v)
      pl[(wave * 16 + lg * 4 + v) * 264 + nf * 16 + la] = (bf16)s[nf][v];
  __syncthreads();
  bf16x8 ap[8];
#pragma unroll
  for (int kk = 0; kk < 8; ++kk)
    ap[kk] = *(const bf16x8*)(pl + (wave * 16 + la) * 264 + kk * 32 + lg * 8);
  f32x4 o[4];
#pragma unroll
  for (int j = 0; j < 4; ++j) o[j] = fzero4();
#pragma unroll
  for (int j = 0; j < 4; ++j)
#pragma unroll
    for (int kk = 0; kk < 8; ++kk) {
      bf16x8 b = *(const bf16x8*)(vT + (j * 16 + la) * 264 + kk * 32 + lg * 8);
      o[j] = mfma16(ap[kk], b, o[j]);
    }
#pragma unroll
  for (int j = 0; j < 4; ++j)
#pragma unroll
    for (int v = 0; v < 4; ++v) {
      int n = qb * 128 + wave * 16 + lg * 4 + v;
      int d = j * 16 + la;
      lout[(size_t)n * 2048 + h * 64 + d] = (bf16)(o[j][v] / den[v]);
    }
}

// ------------- compressed attention (132 keys, padded to 160) ----------------
__global__ __launch_bounds__(512) void k_comp(const bf16* __restrict__ qkv,
                                              const bf16* __restrict__ ckbuf,
                                              bf16* __restrict__ cout) {
  int qb = blockIdx.x, h = blockIdx.y;
  __shared__ __align__(16) bf16 ckl[160 * 72];
  __shared__ __align__(16) bf16 cvT[64 * 168];
  __shared__ __align__(16) bf16 pl[128 * 168];
  int tid = threadIdx.x, wave = tid >> 6, lane = tid & 63;
  int la = lane & 15, lg = lane >> 4;
  const bf16* cks = ckbuf + (size_t)(h * 160) * 64;
  const bf16* cvs = ckbuf + (size_t)((32 + h) * 160) * 64;
  for (int c = tid; c < 1280; c += 512) {
    int row = c >> 3, off = (c & 7) * 8;
    *(bf16x8*)(ckl + row * 72 + off) = *(const bf16x8*)(cks + row * 64 + off);
    bf16x8 vv = *(const bf16x8*)(cvs + row * 64 + off);
#pragma unroll
    for (int e = 0; e < 8; ++e) cvT[(off + e) * 168 + row] = vv[e];
  }
  int nq = qb * 128 + wave * 16 + la;
  bf16x8 aq0 = *(const bf16x8*)(qkv + (size_t)nq * 6144 + h * 64 + lg * 8);
  bf16x8 aq1 = *(const bf16x8*)(qkv + (size_t)nq * 6144 + h * 64 + 32 + lg * 8);
  __syncthreads();
  f32x4 s[10];
#pragma unroll
  for (int nf = 0; nf < 10; ++nf) {
    bf16x8 b0 = *(const bf16x8*)(ckl + (nf * 16 + la) * 72 + lg * 8);
    bf16x8 b1 = *(const bf16x8*)(ckl + (nf * 16 + la) * 72 + 32 + lg * 8);
    f32x4 t = fzero4();
    t = mfma16(aq0, b0, t);
    t = mfma16(aq1, b1, t);
    s[nf] = t;
  }
  int bi = qb * 2 + (wave >> 2);
  float mx[4] = {-1e30f, -1e30f, -1e30f, -1e30f};
#pragma unroll
  for (int nf = 0; nf < 10; ++nf)
#pragma unroll
    for (int v = 0; v < 4; ++v) {
      int jj = nf * 16 + la;
      bool ok = (jj >= 4 + bi) && (jj < 132);
      float sv = ok ? s[nf][v] * 0.125f : -1e30f;
      s[nf][v] = sv;
      mx[v] = fmaxf(mx[v], sv);
    }
#pragma unroll
  for (int v = 0; v < 4; ++v)
#pragma unroll
    for (int m = 1; m < 16; m <<= 1) mx[v] = fmaxf(mx[v], __shfl_xor(mx[v], m, 64));
  float den[4] = {0.f, 0.f, 0.f, 0.f};
#pragma unroll
  for (int nf = 0; nf < 10; ++nf)
#pragma unroll
    for (int v = 0; v < 4; ++v) {
      float p = __expf(s[nf][v] - mx[v]);
      s[nf][v] = p;
      den[v] += p;
    }
#pragma unroll
  for (int v = 0; v < 4; ++v)
#pragma unroll
    for (int m = 1; m < 16; m <<= 1) den[v] += __shfl_xor(den[v], m, 64);
#pragma unroll
  for (int nf = 0; nf < 10; ++nf)
#pragma unroll
    for (int v = 0; v < 4; ++v)
      pl[(wave * 16 + lg * 4 + v) * 168 + nf * 16 + la] = (bf16)s[nf][v];
  __syncthreads();
  bf16x8 ap[5];
#pragma unroll
  for (int kk = 0; kk < 5; ++kk)
    ap[kk] = *(const bf16x8*)(pl + (wave * 16 + la) * 168 + kk * 32 + lg * 8);
  f32x4 o[4];
#pragma unroll
  for (int j = 0; j < 4; ++j) o[j] = fzero4();
#pragma unroll
  for (int j = 0; j < 4; ++j)
#pragma unroll
    for (int kk = 0; kk < 5; ++kk) {
      bf16x8 b = *(const bf16x8*)(cvT + (j * 16 + la) * 168 + kk * 32 + lg * 8);
      o[j] = mfma16(ap[kk], b, o[j]);
    }
#pragma unroll
  for (int j = 0; j < 4; ++j)
#pragma unroll
    for (int v = 0; v < 4; ++v) {
      int n = qb * 128 + wave * 16 + lg * 4 + v;
      int d = j * 16 + la;
      cout[(size_t)n * 2048 + h * 64 + d] = (bf16)(o[j][v] / den[v]);
    }
}

// ------------- combine: att = (s0+s1)*local + s2*comp ------------------------
__global__ __launch_bounds__(256) void k_combine(const bf16* __restrict__ lo,
                                                 const bf16* __restrict__ co,
                                                 const float* __restrict__ comb,
                                                 const float* __restrict__ bcomb,
                                                 bf16* __restrict__ att) {
  size_t idx = (size_t)blockIdx.x * 256 + threadIdx.x;
  size_t base = idx * 8;
  int n = (int)(base >> 11);
  int hd = (int)(base & 2047);
  int h = hd >> 6;
  const float* cb = comb + (size_t)n * 128 + h * 3;
  float s0 = sigm(cb[0] + bcomb[h * 3 + 0]);
  float s1 = sigm(cb[1] + bcomb[h * 3 + 1]);
  float s2 = sigm(cb[2] + bcomb[h * 3 + 2]);
  float wl = s0 + s1;
  bf16x8 l = *(const bf16x8*)(lo + base);
  bf16x8 c = *(const bf16x8*)(co + base);
  bf16x8 r;
#pragma unroll
  for (int e = 0; e < 8; ++e) r[e] = (bf16)(wl * (float)l[e] + s2 * (float)c[e]);
  *(bf16x8*)(att + base) = r;
}

// ============================================================================
extern "C" void kernel_launch(void* const* d_in, const int* in_sizes, int n_in,
                              void* d_out, int out_size, void* d_ws, size_t ws_size,
                              hipStream_t stream) {
  const float* inp = (const float*)d_in[0];
  const float* rmsw = (const float*)d_in[1];
  const float* wqkv = (const float*)d_in[2];
  const float* kpos = (const float*)d_in[3];
  const float* vpos = (const float*)d_in[4];
  const float* kcw = (const float*)d_in[5];
  const float* kcb = (const float*)d_in[6];
  const float* vcw = (const float*)d_in[7];
  const float* vcb = (const float*)d_in[8];
  const float* memkv = (const float*)d_in[9];
  const float* wcomb = (const float*)d_in[10];
  const float* bcomb = (const float*)d_in[11];
  const float* wout = (const float*)d_in[12];
  float* out = (float*)d_out;

  char* ws = (char*)d_ws;
  size_t off = 0;
  auto alloc = [&](size_t bytes) {
    void* p = ws + off;
    off += (bytes + 255) & ~(size_t)255;
    return p;
  };
  bf16* qkv = (bf16*)alloc(100663296);    // [8192][6144]
  bf16* regX = (bf16*)alloc(33554432);    // x_bf16, later att
  bf16* regT1 = (bf16*)alloc(33554432);   // w_qkvT, later comp_out
  bf16* regT2 = (bf16*)alloc(33554432);   // BcT, later local_out
  bf16* woutT = (bf16*)alloc(8388608);    // [2048][2048]
  bf16* wcombT = (bf16*)alloc(524288);    // [128][2048]
  bf16* ckbuf = (bf16*)alloc(1310720);    // [2][32][160][64]
  float* combb = (float*)alloc(4194304);  // [8192][128]

  bf16* xb = regX;
  bf16* wqkvT = regT1;
  bf16* bct = regT2;

  k_rmsnorm<<<8192, 256, 0, stream>>>(inp, rmsw, xb);
  k_transpose<<<dim3(192, 64), 256, 0, stream>>>(wqkv, wqkvT, 2048, 6144, 6144);
  k_transpose<<<dim3(64, 64), 256, 0, stream>>>(wout, woutT, 2048, 2048, 2048);
  k_transpose<<<dim3(4, 64), 256, 0, stream>>>(wcomb, wcombT, 2048, 96, 128);
  k_convwT<<<4096, 256, 0, stream>>>(kcw, vcw, bct);
  // QKV projection: 256^2 8-phase, grid 32x24=768 (%8==0)
  k_gemm256<bf16><<<768, 512, 0, stream>>>(xb, wqkvT, qkv, 8192, 6144, 2048);
  k_gemm<float><<<dim3(1, 64), 256, 0, stream>>>(xb, wcombT, combb, 8192, 128, 2048);
  k_fillck<<<64, 256, 0, stream>>>(memkv, ckbuf);
  k_convgemm<<<64, 256, 0, stream>>>(qkv, kpos, vpos, kcb, vcb, bct, ckbuf);
  bf16* lout = regT2;
  k_local<<<dim3(64, 32), 512, 0, stream>>>(qkv, lout);
  bf16* cout = regT1;
  k_comp<<<dim3(64, 32), 512, 0, stream>>>(qkv, ckbuf, cout);
  bf16* att = regX;
  k_combine<<<8192, 256, 0, stream>>>(lout, cout, combb, bcomb, att);
  // out projection: 256^2 8-phase, grid 32x8=256 (%8==0)
  k_gemm256<float><<<256, 512, 0, stream>>>(att, woutT, out, 8192, 2048, 2048);
  (void)in_sizes; (void)n_in; (void)out_size; (void)ws_size;
}